// Round 8
// baseline (61.602 us; speedup 1.0000x reference)
//
#include <hip/hip_runtime.h>
#include <hip/hip_bf16.h>

// y = upsample_nearest_2x2x2(conv1x1(x,W,b)) == conv on small grid + replicate 8x.
// x: [2][320][16][32][32] f32, W: [160][320] f32, b: [160] f32 -> out: [2][160][32][64][64] f32
//
// v8: store-streaming structure, single kernel.
//  Phase 1: stage full X tile (64 s x 320 k) as bf16 in LDS (pitch 656B), 1 barrier.
//  Phase 2: per M-tile (o-16-group): load W f32 fragments straight from L2, pack to
//  bf16, 10 MFMA, and store that tile's output IMMEDIATELY -> HBM writes flow for
//  ~80% of the kernel instead of a tail burst. No lambdas, static indexing only.

#define CI      320
#define CO      160
#define S_IN    16384        // 16*32*32
#define NT      64           // spatial tile per block
#define NST     10           // K-steps (CI/32)
#define NMT     10           // M-tiles (CO/16)
#define XPITCH  656          // bytes per s-row: 640 data + 16 pad (41x16B chunks)

typedef __attribute__((ext_vector_type(8))) short short8;
typedef __attribute__((ext_vector_type(4))) float f32x4;

union frag_cast { uint4 u; short8 s; };

static __device__ __forceinline__ unsigned short f2bf(float f) {
    __hip_bfloat16 h = __float2bfloat16(f);   // RNE
    unsigned short u;
    __builtin_memcpy(&u, &h, 2);
    return u;
}
static __device__ __forceinline__ unsigned int pack2(float lo, float hi) {
    return (unsigned int)f2bf(lo) | ((unsigned int)f2bf(hi) << 16);
}

__global__ __launch_bounds__(256, 2) void fused_upconv_v8(
    const float* __restrict__ x,
    const float* __restrict__ Wm,
    const float* __restrict__ bias,
    float* __restrict__ out)
{
    __shared__ __align__(16) char Xs[NT * XPITCH];   // 41,984 B

    const int t    = threadIdx.x;
    const int bx   = blockIdx.x;        // 0..511
    const int tile = bx >> 1;           // 0..255
    const int b    = bx & 1;
    const int s_base = tile * NT;
    const float* xb  = x + (size_t)b * CI * S_IN;

    // ---- phase 1: stage X tile (f32 -> bf16, [k][s] -> [s][k] transpose) ----
    // it 0..4: idx = t + it*256 in 0..1279; kq = idx>>4 (k-quad 0..79), sq = idx&15.
    // Loads 4 float4 (k = 4kq..4kq+3, s = sq*4..+3), writes 4 uint2 (k-run of 4).
    #pragma unroll
    for (int it = 0; it < 5; ++it) {
        const int idx = t + it * 256;
        const int kq  = idx >> 4;
        const int sq  = idx & 15;
        const float* p0 = &xb[(size_t)(4 * kq) * S_IN + s_base + sq * 4];
        const float4 a0 = *(const float4*)(p0);
        const float4 a1 = *(const float4*)(p0 + S_IN);
        const float4 a2 = *(const float4*)(p0 + 2 * S_IN);
        const float4 a3 = *(const float4*)(p0 + 3 * S_IN);
        const float e0[4] = {a0.x, a0.y, a0.z, a0.w};
        const float e1[4] = {a1.x, a1.y, a1.z, a1.w};
        const float e2[4] = {a2.x, a2.y, a2.z, a2.w};
        const float e3[4] = {a3.x, a3.y, a3.z, a3.w};
        #pragma unroll
        for (int j = 0; j < 4; ++j) {
            uint2 pr = make_uint2(pack2(e0[j], e1[j]), pack2(e2[j], e3[j]));
            *(uint2*)&Xs[(sq * 4 + j) * XPITCH + kq * 8] = pr;
        }
    }
    __syncthreads();

    const int lane = t & 63;
    const int wid  = t >> 6;            // wave -> 16-s subtile
    const int frow = lane & 15;
    const int fk   = lane >> 4;

    // ---- hoist B-fragments (X) into registers: 10 x short8 = 40 VGPR ----
    short8 bf[NST];
    {
        const char* xrow = &Xs[(wid * 16 + frow) * XPITCH + fk * 16];
        #pragma unroll
        for (int st = 0; st < NST; ++st)
            bf[st] = *(const short8*)(xrow + st * 64);
    }

    // ---- epilogue indices (constant across mt) ----
    const int s   = s_base + wid * 16 + frow;   // D col = s
    const int dd  = s >> 10;                    // constant per block
    const int hh  = (s >> 5) & 31;
    const int wc0 = (s & 31) & ~1;
    const int odd = lane & 1;
    const size_t ob = (size_t)b * CO;

    // ---- phase 2: per-M-tile K-sweep + immediate stores (no barriers) ----
    #pragma unroll
    for (int mt = 0; mt < NMT; ++mt) {
        // A-fragments: W[o = mt*16+frow][k = st*32 + fk*8 .. +7], f32 -> bf16 pack
        const float* wrow = &Wm[(size_t)(mt * 16 + frow) * CI + fk * 8];
        short8 af[NST];
        #pragma unroll
        for (int st = 0; st < NST; ++st) {
            const float4 f0 = *(const float4*)(wrow + st * 32);
            const float4 f1 = *(const float4*)(wrow + st * 32 + 4);
            frag_cast fc;
            fc.u = (uint4){pack2(f0.x, f0.y), pack2(f0.z, f0.w),
                           pack2(f1.x, f1.y), pack2(f1.z, f1.w)};
            af[st] = fc.s;
        }

        f32x4 acc0 = {0.f, 0.f, 0.f, 0.f};
        f32x4 acc1 = {0.f, 0.f, 0.f, 0.f};
        #pragma unroll
        for (int st = 0; st < NST; st += 2) {
            acc0 = __builtin_amdgcn_mfma_f32_16x16x32_bf16(af[st],     bf[st],     acc0, 0, 0, 0);
            acc1 = __builtin_amdgcn_mfma_f32_16x16x32_bf16(af[st + 1], bf[st + 1], acc1, 0, 0, 0);
        }

        const float4 bv = *(const float4*)&bias[mt * 16 + fk * 4];
        const float bvj[4] = {bv.x, bv.y, bv.z, bv.w};
        #pragma unroll
        for (int j = 0; j < 4; ++j) {
            const int o = mt * 16 + fk * 4 + j;     // D row = o
            float v  = acc0[j] + acc1[j] + bvj[j];
            float vp = __shfl_xor(v, 1);
            float lo = odd ? vp : v;
            float hi = odd ? v : vp;
            f32x4 q = {lo, lo, hi, hi};
            // even lane -> d-row 2dd, odd -> 2dd+1; each writes h-rows 2hh, 2hh+1
            const size_t base = ((ob + o) * 32 + (size_t)(2 * dd + odd)) * 4096
                              + (size_t)(2 * hh) * 64 + (size_t)(2 * wc0);
            __builtin_nontemporal_store(q, (f32x4*)&out[base]);
            __builtin_nontemporal_store(q, (f32x4*)&out[base + 64]);
        }
    }
}

extern "C" void kernel_launch(void* const* d_in, const int* in_sizes, int n_in,
                              void* d_out, int out_size, void* d_ws, size_t ws_size,
                              hipStream_t stream) {
    const float* x    = (const float*)d_in[0];
    const float* Wm   = (const float*)d_in[1];
    const float* bias = (const float*)d_in[2];
    float* out        = (float*)d_out;

    fused_upconv_v8<<<dim3(512), dim3(256), 0, stream>>>(x, Wm, bias, out);
}

// Round 9
// 38.671 us; speedup vs baseline: 1.5930x; 1.5930x over previous
//
#include <hip/hip_runtime.h>
#include <hip/hip_bf16.h>

// y = upsample_nearest_2x2x2(conv1x1(x,W,b)); conv on small grid via bf16 MFMA, replicate 8x.
// x: [2][320][16][32][32] f32, W: [160][320] f32, b: [160] f32 -> out: [2][160][32][64][64] f32
//
// v9 = round-2 kernel (proven 40.3us) with ONE change: double-buffered LDS ->
// 1 barrier per K-chunk instead of 2. Prefetch issued after the barrier so the
// compiler's vmcnt(0) drain at the barrier never waits on fresh loads.

#define CI     320
#define CO     160
#define S_IN   16384      // 16*32*32
#define KC     32         // K chunk = one MFMA K-step
#define NT     64         // spatial tile per block
#define NCHUNK (CI / KC)  // 10
#define MT     (CO / 16)  // 10 M-tiles

typedef __attribute__((ext_vector_type(8))) short short8;
typedef __attribute__((ext_vector_type(4))) float f32x4;

static __device__ __forceinline__ unsigned short f2bf(float f) {
    __hip_bfloat16 h = __float2bfloat16(f);   // RNE
    unsigned short u;
    __builtin_memcpy(&u, &h, 2);
    return u;
}
static __device__ __forceinline__ unsigned int pack2(float lo, float hi) {
    return (unsigned int)f2bf(lo) | ((unsigned int)f2bf(hi) << 16);
}

__global__ __launch_bounds__(256) void fused_upconv_v9(
    const float* __restrict__ x,
    const float* __restrict__ Wm,
    const float* __restrict__ bias,
    float* __restrict__ out)
{
    // bf16 tiles, rows padded to 80 B (20 u32) — R2's proven layout, x2 buffers
    __shared__ unsigned int XsU[2][NT][20];   // [buf][s][k/2]  10 KB
    __shared__ unsigned int WsU[2][CO][20];   // [buf][o][k/2]  25 KB

    const int t      = threadIdx.x;
    const int tile   = blockIdx.x;          // 0..255
    const int b      = blockIdx.y;          // 0..1
    const int s_base = tile * NT;
    const float* xb  = x + (size_t)b * CI * S_IN;

    // ---- staging maps (identical to R2) ----
    const int kp = t >> 4;              // k-pair 0..15
    const int s4 = (t & 15) * 4;        // s-quad base
    const int ow = t >> 3;              // W o-base 0..31
    const int kq = t & 7;               // W k-quad 0..7

    float4 xr0, xr1;
    float4 wr[5];

    // prefetch chunk 0
    {
        xr0 = *(const float4*)&xb[(size_t)(2 * kp)     * S_IN + s_base + s4];
        xr1 = *(const float4*)&xb[(size_t)(2 * kp + 1) * S_IN + s_base + s4];
        #pragma unroll
        for (int it = 0; it < 5; ++it)
            wr[it] = *(const float4*)&Wm[(size_t)(ow + it * 32) * CI + kq * 4];
    }

    // ---- fragment indices (identical to R2) ----
    const int lane = t & 63;
    const int wid  = t >> 6;        // wave -> 16-s subtile
    const int frow = lane & 15;
    const int fk   = lane >> 4;

    f32x4 acc[MT];
    #pragma unroll
    for (int mt = 0; mt < MT; ++mt) acc[mt] = (f32x4){0.f, 0.f, 0.f, 0.f};

    for (int c = 0; c < NCHUNK; ++c) {
        const int bs = c & 1;

        // stage regs -> LDS buf[bs] (pack2 consumes the loads -> vmcnt drained here)
        {
            float xa[4] = {xr0.x, xr0.y, xr0.z, xr0.w};
            float xc[4] = {xr1.x, xr1.y, xr1.z, xr1.w};
            #pragma unroll
            for (int j = 0; j < 4; ++j)
                XsU[bs][s4 + j][kp] = pack2(xa[j], xc[j]);   // k=2kp low, 2kp+1 high
            #pragma unroll
            for (int it = 0; it < 5; ++it) {
                uint2 p = make_uint2(pack2(wr[it].x, wr[it].y), pack2(wr[it].z, wr[it].w));
                *(uint2*)&WsU[bs][ow + it * 32][kq * 2] = p;
            }
        }
        __syncthreads();   // single barrier: publishes buf[bs]; vmcnt already drained

        // issue prefetch of chunk c+1 AFTER the barrier (overlaps MFMA below)
        if (c < NCHUNK - 1) {
            const int kc = (c + 1) * KC;
            xr0 = *(const float4*)&xb[(size_t)(kc + 2 * kp)     * S_IN + s_base + s4];
            xr1 = *(const float4*)&xb[(size_t)(kc + 2 * kp + 1) * S_IN + s_base + s4];
            #pragma unroll
            for (int it = 0; it < 5; ++it)
                wr[it] = *(const float4*)&Wm[(size_t)(ow + it * 32) * CI + kc + kq * 4];
        }

        // compute chunk c from buf[bs]
        const short8 bfrag =
            *(const short8*)((const char*)(&XsU[bs][wid * 16 + frow][0]) + fk * 16);
        #pragma unroll
        for (int mt = 0; mt < MT; ++mt) {
            const short8 afrag =
                *(const short8*)((const char*)(&WsU[bs][mt * 16 + frow][0]) + fk * 16);
            acc[mt] = __builtin_amdgcn_mfma_f32_16x16x32_bf16(afrag, bfrag, acc[mt], 0, 0, 0);
        }
        // NOTE: no second barrier. Next iteration writes buf[bs^1]; a wave can only
        // reach iteration c+2 (reusing buf[bs]) after ALL waves passed barrier c+1,
        // which is after their chunk-c reads completed -> race-free.
    }

    // ---- epilogue (identical to R2): bias + replicate 8x; shfl-pair float4 stores ----
    const int s   = s_base + wid * 16 + frow;   // D col = s
    const int dd  = s >> 10;
    const int hh  = (s >> 5) & 31;
    const int wc  = s & 31;
    const int odd = lane & 1;
    const int wc0 = wc & ~1;

    #pragma unroll
    for (int mt = 0; mt < MT; ++mt) {
        #pragma unroll
        for (int j = 0; j < 4; ++j) {
            const int o = mt * 16 + fk * 4 + j; // D row = o
            float v  = acc[mt][j] + bias[o];
            float vp = __shfl_xor(v, 1);
            float lo = odd ? vp : v;
            float hi = odd ? v : vp;
            float4 q = make_float4(lo, lo, hi, hi);
            const size_t base = (((size_t)(b * CO + o) * 32) + (size_t)(2 * dd + odd)) * 4096
                              + (size_t)(2 * hh) * 64 + (size_t)(2 * wc0);
            *(float4*)&out[base]      = q;
            *(float4*)&out[base + 64] = q;
        }
    }
}

extern "C" void kernel_launch(void* const* d_in, const int* in_sizes, int n_in,
                              void* d_out, int out_size, void* d_ws, size_t ws_size,
                              hipStream_t stream) {
    const float* x    = (const float*)d_in[0];
    const float* Wm   = (const float*)d_in[1];
    const float* bias = (const float*)d_in[2];
    float* out        = (float*)d_out;

    dim3 grid(S_IN / NT, 2);   // (256, 2) = 512 blocks
    dim3 block(256);
    fused_upconv_v9<<<grid, block, 0, stream>>>(x, Wm, bias, out);
}